// Round 10
// baseline (111.175 us; speedup 1.0000x reference)
//
#include <hip/hip_runtime.h>
#include <hip/hip_bf16.h>

// ---------- constants (problem is fully static) ----------
#define NQ  13294
#define NV  13294
#define BQ  26588          // B * NQ
#define NEL 6806528        // BQ * 256

typedef __attribute__((ext_vector_type(8))) short short8;
typedef __attribute__((ext_vector_type(4))) float f32x4;

static __device__ __forceinline__ ushort f2bf(float f) {
    unsigned int x = __float_as_uint(f);
    unsigned int r = (x + 0x7fffu + ((x >> 16) & 1u)) >> 16;
    return (ushort)r;
}
static __device__ __forceinline__ uint cvtpk_bf16(float a, float b) {
    uint r;
    asm("v_cvt_pk_bf16_f32 %0, %1, %2" : "=v"(r) : "v"(a), "v"(b));
    return r;   // lo16 = bf16(a), hi16 = bf16(b)
}
static __device__ __forceinline__ uint cvtpk_f16(float a, float b) {
    uint r;
    asm("v_cvt_pkrtz_f16_f32 %0, %1, %2" : "=v"(r) : "v"(a), "v"(b));
    return r;   // lo16 = f16(a), hi16 = f16(b)
}
static __device__ __forceinline__ float f16lo(uint u) {
    _Float16 h; ushort t = (ushort)(u & 0xffffu);
    __builtin_memcpy(&h, &t, 2); return (float)h;
}
static __device__ __forceinline__ float f16hi(uint u) {
    _Float16 h; ushort t = (ushort)(u >> 16);
    __builtin_memcpy(&h, &t, 2); return (float)h;
}
// acc(f32) += f16(sel of g) * f16(sel of w) -- single VOP3P mix op
static __device__ __forceinline__ float fmamix_ll(float acc, uint g, uint w) {
    asm("v_fma_mix_f32 %0, %1, %2, %0 op_sel:[0,0,0] op_sel_hi:[1,1,0]" : "+v"(acc) : "v"(g), "v"(w));
    return acc;
}
static __device__ __forceinline__ float fmamix_hl(float acc, uint g, uint w) {
    asm("v_fma_mix_f32 %0, %1, %2, %0 op_sel:[1,0,0] op_sel_hi:[1,1,0]" : "+v"(acc) : "v"(g), "v"(w));
    return acc;
}
static __device__ __forceinline__ float fmamix_lh(float acc, uint g, uint w) {
    asm("v_fma_mix_f32 %0, %1, %2, %0 op_sel:[0,1,0] op_sel_hi:[1,1,0]" : "+v"(acc) : "v"(g), "v"(w));
    return acc;
}
static __device__ __forceinline__ float fmamix_hh(float acc, uint g, uint w) {
    asm("v_fma_mix_f32 %0, %1, %2, %0 op_sel:[1,1,0] op_sel_hi:[1,1,0]" : "+v"(acc) : "v"(g), "v"(w));
    return acc;
}
// async global->LDS, 16B per lane; LDS dest is wave-uniform base + lane*16
static __device__ __forceinline__ void gload_lds16(const void* g, void* l) {
    __builtin_amdgcn_global_load_lds(
        (const __attribute__((address_space(1))) uint*)g,
        (__attribute__((address_space(3))) uint*)l, 16, 0, 0);
}

// ---------- prep: weight transpose (blk<56), biases (56), f32->bf16 cvt (57+) ----------
__global__ __launch_bounds__(256) void prep_all(
    const float* __restrict__ Wv, const float* __restrict__ Wo,
    const float* __restrict__ Wa, const float* __restrict__ Wu,
    const float* __restrict__ bo, const float* __restrict__ ba,
    const float* __restrict__ value, const float* __restrict__ query,
    ushort* __restrict__ tWv, ushort* __restrict__ tWoa,
    ushort* __restrict__ tWu, float* __restrict__ boa,
    ushort* __restrict__ v_bf, ushort* __restrict__ q_bf) {
    const int blk = blockIdx.x;
    const int tid = threadIdx.x;
    if (blk >= 57) {                     // streaming f32->bf16, 8 floats/thread
        int i8 = (blk - 57) * 2048 + tid * 8;
        const float* src; ushort* dst; int off;
        if (i8 < NEL) { src = value; dst = v_bf; off = i8; }
        else          { src = query; dst = q_bf; off = i8 - NEL; }
        float4 f0 = *reinterpret_cast<const float4*>(src + off);
        float4 f1 = *reinterpret_cast<const float4*>(src + off + 4);
        uint4 o;
        o.x = cvtpk_bf16(f0.x, f0.y);
        o.y = cvtpk_bf16(f0.z, f0.w);
        o.z = cvtpk_bf16(f1.x, f1.y);
        o.w = cvtpk_bf16(f1.z, f1.w);
        *reinterpret_cast<uint4*>(dst + off) = o;
        return;
    }
    if (blk == 56) {                     // biases
        if (tid < 256) boa[tid] = bo[tid];
        int j = tid + 256;
        if (j < 384) boa[j] = ba[j - 256];
        return;
    }
    __shared__ float t[64][65];
    const float* src; ushort* dst; int srcN, k0, n0, drow0;
    if (blk < 16)      { int u = blk;      src = Wv; srcN = 256; dst = tWv;  k0 = (u >> 2) * 64; n0 = (u & 3) * 64; drow0 = n0; }
    else if (blk < 32) { int u = blk - 16; src = Wo; srcN = 256; dst = tWoa; k0 = (u >> 2) * 64; n0 = (u & 3) * 64; drow0 = n0; }
    else if (blk < 40) { int u = blk - 32; src = Wa; srcN = 128; dst = tWoa; k0 = (u >> 1) * 64; n0 = (u & 1) * 64; drow0 = 256 + n0; }
    else               { int u = blk - 40; src = Wu; srcN = 256; dst = tWu;  k0 = (u >> 2) * 64; n0 = (u & 3) * 64; drow0 = n0; }
#pragma unroll
    for (int it = 0; it < 16; ++it) {
        int idx = tid + it * 256, r = idx >> 6, c = idx & 63;
        t[r][c] = src[(size_t)(k0 + r) * srcN + n0 + c];     // coalesced read
    }
    __syncthreads();
#pragma unroll
    for (int it = 0; it < 16; ++it) {
        int idx = tid + it * 256, r = idx >> 6, c = idx & 63;
        dst[(size_t)(drow0 + r) * 256 + k0 + c] = f2bf(t[c][r]);  // coalesced write
    }
}

// ---------- GEMM core v4: all-bf16, dual global_load_lds, swizzled linear LDS ----------
// Tile 128x128, BK=32, 4 waves (2x2), wave 64x64 = 4x4 frags of 16x16x32.
// LDS buffer = [128 rows][64B] linear; chunk swizzle c' = (c + (R>>1)) & 3
// applied via the per-lane GLOBAL source address (store) and read offset:
// each 16-lane fragment read then covers all 8 16B-columns -> conflict-free.
// out_mode: 0 = f32 [M,N]; 2 = fp16 [M,N]; 3 = fp16 scattered to
//           vproj_t[(b*8+h)*NV + pix][32] with h=col>>5, ch=col&31.
static __device__ __forceinline__ void gemm_core4(
    const ushort* __restrict__ Ab, const ushort* __restrict__ Bt,
    const float* __restrict__ bias, void* __restrict__ Cout,
    int M, int N, int out_mode, int mblk, int nblk,
    ushort* sA, ushort* sB) {
    const int tid = threadIdx.x;
    const int wid = tid >> 6;
    const int lane = tid & 63;
    const int row0 = mblk * 128;
    const int col0 = nblk * 128;
    const int wr = (wid >> 1) * 64;
    const int wc = (wid & 1) * 64;

    f32x4 acc[4][4];
#pragma unroll
    for (int m = 0; m < 4; ++m)
#pragma unroll
        for (int n = 0; n < 4; ++n) acc[m][n] = (f32x4){0.f, 0.f, 0.f, 0.f};

    auto GL = [&](int t) {               // stage K-slice t into buf t&1 (A and B)
        int buf = t & 1;
#pragma unroll
        for (int i = 0; i < 2; ++i) {
            int rbase16 = 32 * wid + 16 * i;
            int rloc = rbase16 + (lane >> 2);
            int csrc = ((lane & 3) - (rloc >> 1)) & 3;
            size_t koff = (size_t)t * 64 + csrc * 16;
            int gr = row0 + rloc; gr = gr < M ? gr : M - 1;
            gload_lds16((const char*)Ab + (size_t)gr * 512 + koff,
                        (char*)sA + buf * 8192 + rbase16 * 64);
            int gc = col0 + rloc;        // N multiple of 128
            gload_lds16((const char*)Bt + (size_t)gc * 512 + koff,
                        (char*)sB + buf * 8192 + rbase16 * 64);
        }
    };
    auto COMPUTE = [&](int t) {
        int buf = t & 1;
        const int rbase = lane & 15;
        const int g = lane >> 4;
        short8 a[4], b[4];
#pragma unroll
        for (int m = 0; m < 4; ++m) {
            int R = wr + m * 16 + rbase;
            a[m] = *reinterpret_cast<const short8*>(
                (char*)sA + buf * 8192 + R * 64 + (((g + (R >> 1)) & 3) << 4));
        }
#pragma unroll
        for (int n = 0; n < 4; ++n) {
            int R = wc + n * 16 + rbase;
            b[n] = *reinterpret_cast<const short8*>(
                (char*)sB + buf * 8192 + R * 64 + (((g + (R >> 1)) & 3) << 4));
        }
#pragma unroll
        for (int m = 0; m < 4; ++m)
#pragma unroll
            for (int n = 0; n < 4; ++n)
                acc[m][n] = __builtin_amdgcn_mfma_f32_16x16x32_bf16(a[m], b[n], acc[m][n], 0, 0, 0);
    };

    GL(0);
#pragma unroll
    for (int t = 0; t < 8; ++t) {
        __syncthreads();                 // vmcnt-drained: buf t&1 staged
        if (t < 7) GL(t + 1);            // lands during COMPUTE(t)
        COMPUTE(t);
    }

    // epilogue: lane holds C[row=(lane>>4)*4+j][col=lane&15] per fragment
    const int lr = (lane >> 4) * 4;
    const int lc = lane & 15;
#pragma unroll
    for (int m = 0; m < 4; ++m) {
#pragma unroll
        for (int n = 0; n < 4; ++n) {
            int gcol = col0 + wc + n * 16 + lc;
            float bv = bias[gcol];
#pragma unroll
            for (int j = 0; j < 4; ++j) {
                int grow = row0 + wr + m * 16 + lr + j;
                if (grow < M) {
                    float vv = acc[m][n][j] + bv;
                    if (out_mode == 0) {
                        ((float*)Cout)[(size_t)grow * N + gcol] = vv;
                    } else if (out_mode == 2) {
                        ((ushort*)Cout)[(size_t)grow * N + gcol] = (ushort)(cvtpk_f16(vv, vv) & 0xffffu);
                    } else {   // mode 3: transposed fp16 value layout [b*8+h][pix][32]
                        int bb = grow >= NV;
                        int pix = grow - bb * NV;
                        int h = gcol >> 5, ch = gcol & 31;
                        ((ushort*)Cout)[(((size_t)(bb * 8 + h)) * NV + pix) * 32 + ch] =
                            (ushort)(cvtpk_f16(vv, vv) & 0xffffu);
                    }
                }
            }
        }
    }
}

// merged GEMM1 (v_bf->vproj_t fp16, y=0..1) + GEMM2 (q_bf->offattn fp16, y=2..4)
__global__ __launch_bounds__(256, 4) void gemm_fused(
    const ushort* __restrict__ v_bf, const ushort* __restrict__ q_bf,
    const ushort* __restrict__ tWv, const ushort* __restrict__ tWoa,
    const float* __restrict__ bval, const float* __restrict__ boa,
    ushort* __restrict__ vproj_t, ushort* __restrict__ offattn) {
    __shared__ ushort sA[2 * 4096];
    __shared__ ushort sB[2 * 4096];
    const bool g1 = blockIdx.y < 2;
    gemm_core4(g1 ? v_bf : q_bf, g1 ? tWv : tWoa, g1 ? bval : boa,
               g1 ? (void*)vproj_t : (void*)offattn,
               BQ, g1 ? 256 : 384, g1 ? 3 : 2,
               blockIdx.x, g1 ? blockIdx.y : blockIdx.y - 2, sA, sB);
}

__global__ __launch_bounds__(256, 4) void gemm_out(
    const ushort* __restrict__ outacc, const ushort* __restrict__ tWu,
    const float* __restrict__ bout, float* __restrict__ dout) {
    __shared__ ushort sA[2 * 4096];
    __shared__ ushort sB[2 * 4096];
    gemm_core4(outacc, tWu, bout, dout, BQ, 256, 0, blockIdx.x, blockIdx.y, sA, sB);
}

// ---------- softmax + bilinear sampling + head-weighted accumulation ----------
// (unchanged: at its memory-system roofline, 54us invariant across 3 structures)
__global__ __launch_bounds__(256, 4) void msda_sample(
    const ushort* __restrict__ offattn,  // fp16 [BQ, 384] : 256 offsets + 128 logits
    const float* __restrict__ refp,      // [B, NQ, 4, 2]
    const ushort* __restrict__ vt,       // fp16 [B*8][NV][32]
    ushort* __restrict__ out_acc) {      // bf16 [BQ, 256]
    __shared__ int2 s_ad[4][256];        // 8KB : (addr_row0, addr_row1)
    __shared__ uint s_w[4][256];         // 4KB : packed f16 (w_y0, w_y1)

    const int tid = threadIdx.x;
    const int qi = tid >> 6;
    const int lane = tid & 63;
    const int bq = blockIdx.x * 4 + qi;  // 26588 = 4 * 6647 exact
    const int b = bq / NQ;
    const int q = bq - b * NQ;
    const int h = lane >> 3;

    const ushort* oa = offattn + (size_t)bq * 384;
    const int t0 = lane * 2;             // t = h*16 + s
    uint lgu = *reinterpret_cast<const uint*>(oa + 256 + t0);
    float lg0 = f16lo(lgu), lg1 = f16hi(lgu);
    float m = fmaxf(lg0, lg1);
    m = fmaxf(m, __shfl_xor(m, 1));
    m = fmaxf(m, __shfl_xor(m, 2));
    m = fmaxf(m, __shfl_xor(m, 4));      // max over the head's 16 logits
    float e0 = __expf(lg0 - m), e1 = __expf(lg1 - m);
    float ssum = e0 + e1;
    ssum += __shfl_xor(ssum, 1);
    ssum += __shfl_xor(ssum, 2);
    ssum += __shfl_xor(ssum, 4);
    float inv = 1.f / ssum;

    uint2 offu = *reinterpret_cast<const uint2*>(oa + 2 * t0);  // 4 fp16
    const int l = (t0 >> 2) & 3;
    const int   Wi = (l == 0) ? 100 : (l == 1) ? 50 : (l == 2) ? 25 : 13;
    const int   st = (l == 0) ? 0 : (l == 1) ? 10000 : (l == 2) ? 12500 : 13125;
    const float Wf = (float)Wi;
    float rx = refp[(((size_t)b * NQ + q) * 4 + l) * 2 + 0];
    float ry = refp[(((size_t)b * NQ + q) * 4 + l) * 2 + 1];
    const int vbase = (b * 8 + h) * NV * 64;      // byte base of this head's plane

#pragma unroll
    for (int j = 0; j < 2; ++j) {
        float e = (j ? e1 : e0) * inv;
        float ox = j ? f16lo(offu.y) : f16lo(offu.x);
        float oy = j ? f16hi(offu.y) : f16hi(offu.x);
        float x = fmaf(rx, Wf, ox) - 0.5f;
        float y = fmaf(ry, Wf, oy) - 0.5f;
        float x0f = floorf(x), y0f = floorf(y);
        float fx = x - x0f, fy = y - y0f;
        int x0 = (int)x0f, y0 = (int)y0f;
        float wx0 = (x0 >= 0 && x0 < Wi)         ? e * (1.f - fx) : 0.f;
        float wx1 = (x0 + 1 >= 0 && x0 + 1 < Wi) ? e * fx         : 0.f;
        float wy0 = (y0 >= 0 && y0 < Wi)         ? (1.f - fy) : 0.f;
        float wy1 = (y0 + 1 >= 0 && y0 + 1 < Wi) ? fy         : 0.f;
        int px0 = min(max(x0, 0), Wi - 1) * 64;
        int px1 = min(max(x0 + 1, 0), Wi - 1) * 64;
        int a0 = vbase + (st + min(max(y0, 0), Wi - 1) * Wi) * 64;
        int a1 = vbase + (st + min(max(y0 + 1, 0), Wi - 1) * Wi) * 64;
        int s = 2 * (lane & 7) + j;
        int u = ((s ^ h) << 4) + (h << 1);
        s_ad[qi][u]     = make_int2(a0 + px0, a1 + px0);
        s_ad[qi][u + 1] = make_int2(a0 + px1, a1 + px1);
        s_w[qi][u]      = cvtpk_f16(wx0 * wy0, wx0 * wy1);
        s_w[qi][u + 1]  = cvtpk_f16(wx1 * wy0, wx1 * wy1);
    }
    __syncthreads();

    const int xbit = (lane >> 2) & 1;
    const int cg16 = (lane & 3) * 16;
    const char* vtc = (const char*)vt;

    int2 A[16]; uint Wp[16];
#pragma unroll
    for (int ss = 0; ss < 16; ++ss) {
        int u = ((ss ^ h) << 4) + (h << 1) + xbit;
        int2 a = s_ad[qi][u];
        A[ss] = make_int2(a.x + cg16, a.y + cg16);
        Wp[ss] = s_w[qi][u];
    }

    float acc[8] = {0.f, 0.f, 0.f, 0.f, 0.f, 0.f, 0.f, 0.f};
#pragma unroll
    for (int ss = 0; ss < 16; ++ss) {
        uint4 g0 = *reinterpret_cast<const uint4*>(vtc + (uint)A[ss].x);
        uint4 g1 = *reinterpret_cast<const uint4*>(vtc + (uint)A[ss].y);
        uint w = Wp[ss];
        acc[0] = fmamix_ll(acc[0], g0.x, w); acc[1] = fmamix_hl(acc[1], g0.x, w);
        acc[2] = fmamix_ll(acc[2], g0.y, w); acc[3] = fmamix_hl(acc[3], g0.y, w);
        acc[4] = fmamix_ll(acc[4], g0.z, w); acc[5] = fmamix_hl(acc[5], g0.z, w);
        acc[6] = fmamix_ll(acc[6], g0.w, w); acc[7] = fmamix_hl(acc[7], g0.w, w);
        acc[0] = fmamix_lh(acc[0], g1.x, w); acc[1] = fmamix_hh(acc[1], g1.x, w);
        acc[2] = fmamix_lh(acc[2], g1.y, w); acc[3] = fmamix_hh(acc[3], g1.y, w);
        acc[4] = fmamix_lh(acc[4], g1.z, w); acc[5] = fmamix_hh(acc[5], g1.z, w);
        acc[6] = fmamix_lh(acc[6], g1.w, w); acc[7] = fmamix_hh(acc[7], g1.w, w);
    }

#pragma unroll
    for (int i = 0; i < 8; ++i) acc[i] += __shfl_xor(acc[i], 4);   // sum x-corners
    if (xbit == 0) {
        uint4 o;
        o.x = cvtpk_bf16(acc[0], acc[1]);
        o.y = cvtpk_bf16(acc[2], acc[3]);
        o.z = cvtpk_bf16(acc[4], acc[5]);
        o.w = cvtpk_bf16(acc[6], acc[7]);
        *reinterpret_cast<uint4*>(out_acc + (size_t)bq * 256 + h * 32 + (lane & 3) * 8) = o;
    }
}

// ---------- launch ----------
extern "C" void kernel_launch(void* const* d_in, const int* in_sizes, int n_in,
                              void* d_out, int out_size, void* d_ws, size_t ws_size,
                              hipStream_t stream) {
    const float* query  = (const float*)d_in[0];
    const float* value  = (const float*)d_in[1];
    const float* refp   = (const float*)d_in[2];
    const float* W_off  = (const float*)d_in[5];
    const float* b_off  = (const float*)d_in[6];
    const float* W_attn = (const float*)d_in[7];
    const float* b_attn = (const float*)d_in[8];
    const float* W_val  = (const float*)d_in[9];
    const float* b_val  = (const float*)d_in[10];
    const float* W_out  = (const float*)d_in[11];
    const float* b_out  = (const float*)d_in[12];

    const size_t ROWB = (size_t)BQ * 256 * 2;   // bytes of one 16-bit [BQ,256] buffer
    char* ws = (char*)d_ws;
    ushort* vproj_t = (ushort*)(ws);                               // [B*8][NV][32] fp16
    ushort* outacc  = (ushort*)(ws + ROWB);                        // [BQ,256] bf16
    ushort* v_bf    = (ushort*)(ws + 2 * ROWB);                    // [BQ,256] bf16
    ushort* q_bf    = (ushort*)(ws + 3 * ROWB);                    // [BQ,256] bf16
    ushort* offattn = (ushort*)(ws + 4 * ROWB);                    // [BQ,384] fp16
    char*   wbase   = ws + 4 * ROWB + (size_t)BQ * 384 * 2;
    ushort* tWv  = (ushort*)(wbase);
    ushort* tWoa = tWv + 65536;
    ushort* tWu  = tWoa + 98304;
    float*  boa  = (float*)(tWu + 65536);

    prep_all<<<57 + 6647, 256, 0, stream>>>(
        W_val, W_off, W_attn, W_out, b_off, b_attn, value, query,
        tWv, tWoa, tWu, boa, v_bf, q_bf);

    gemm_fused<<<dim3(208, 5), 256, 0, stream>>>(
        v_bf, q_bf, tWv, tWoa, b_val, boa, vproj_t, offattn);

    msda_sample<<<BQ / 4, 256, 0, stream>>>(offattn, refp, vproj_t, outacc);

    gemm_out<<<dim3(208, 2), 256, 0, stream>>>(outacc, tWu, b_out, (float*)d_out);
}

// Round 11
// 102.303 us; speedup vs baseline: 1.0867x; 1.0867x over previous
//
#include <hip/hip_runtime.h>
#include <hip/hip_bf16.h>

// ---------- constants (problem is fully static) ----------
#define NQ  13294
#define NV  13294
#define BQ  26588          // B * NQ

typedef __attribute__((ext_vector_type(8))) short short8;
typedef __attribute__((ext_vector_type(4))) float f32x4;

static __device__ __forceinline__ ushort f2bf(float f) {
    unsigned int x = __float_as_uint(f);
    unsigned int r = (x + 0x7fffu + ((x >> 16) & 1u)) >> 16;
    return (ushort)r;
}
static __device__ __forceinline__ uint cvtpk_bf16(float a, float b) {
    uint r;
    asm("v_cvt_pk_bf16_f32 %0, %1, %2" : "=v"(r) : "v"(a), "v"(b));
    return r;   // lo16 = bf16(a), hi16 = bf16(b)
}
static __device__ __forceinline__ uint cvtpk_f16(float a, float b) {
    uint r;
    asm("v_cvt_pkrtz_f16_f32 %0, %1, %2" : "=v"(r) : "v"(a), "v"(b));
    return r;   // lo16 = f16(a), hi16 = f16(b)
}
static __device__ __forceinline__ float f16lo(uint u) {
    _Float16 h; ushort t = (ushort)(u & 0xffffu);
    __builtin_memcpy(&h, &t, 2); return (float)h;
}
static __device__ __forceinline__ float f16hi(uint u) {
    _Float16 h; ushort t = (ushort)(u >> 16);
    __builtin_memcpy(&h, &t, 2); return (float)h;
}
// acc(f32) += f16(sel of g) * f16(sel of w) -- single VOP3P mix op
static __device__ __forceinline__ float fmamix_ll(float acc, uint g, uint w) {
    asm("v_fma_mix_f32 %0, %1, %2, %0 op_sel:[0,0,0] op_sel_hi:[1,1,0]" : "+v"(acc) : "v"(g), "v"(w));
    return acc;
}
static __device__ __forceinline__ float fmamix_hl(float acc, uint g, uint w) {
    asm("v_fma_mix_f32 %0, %1, %2, %0 op_sel:[1,0,0] op_sel_hi:[1,1,0]" : "+v"(acc) : "v"(g), "v"(w));
    return acc;
}
static __device__ __forceinline__ float fmamix_lh(float acc, uint g, uint w) {
    asm("v_fma_mix_f32 %0, %1, %2, %0 op_sel:[0,1,0] op_sel_hi:[1,1,0]" : "+v"(acc) : "v"(g), "v"(w));
    return acc;
}
static __device__ __forceinline__ float fmamix_hh(float acc, uint g, uint w) {
    asm("v_fma_mix_f32 %0, %1, %2, %0 op_sel:[1,1,0] op_sel_hi:[1,1,0]" : "+v"(acc) : "v"(g), "v"(w));
    return acc;
}

// ---------- weight prep: coalesced 64x64 LDS-tile transpose ----------
__global__ __launch_bounds__(256) void prep_weights(
    const float* __restrict__ Wv, const float* __restrict__ Wo,
    const float* __restrict__ Wa, const float* __restrict__ Wu,
    const float* __restrict__ bo, const float* __restrict__ ba,
    ushort* __restrict__ tWv, ushort* __restrict__ tWoa,
    ushort* __restrict__ tWu, float* __restrict__ boa) {
    const int blk = blockIdx.x;
    const int tid = threadIdx.x;
    if (blk == 56) {               // biases
        if (tid < 256) boa[tid] = bo[tid];
        int j = tid + 256;
        if (j < 384) boa[j] = ba[j - 256];
        return;
    }
    __shared__ float t[64][65];
    const float* src; ushort* dst; int srcN, k0, n0, drow0;
    if (blk < 16)      { int u = blk;      src = Wv; srcN = 256; dst = tWv;  k0 = (u >> 2) * 64; n0 = (u & 3) * 64; drow0 = n0; }
    else if (blk < 32) { int u = blk - 16; src = Wo; srcN = 256; dst = tWoa; k0 = (u >> 2) * 64; n0 = (u & 3) * 64; drow0 = n0; }
    else if (blk < 40) { int u = blk - 32; src = Wa; srcN = 128; dst = tWoa; k0 = (u >> 1) * 64; n0 = (u & 1) * 64; drow0 = 256 + n0; }
    else               { int u = blk - 40; src = Wu; srcN = 256; dst = tWu;  k0 = (u >> 2) * 64; n0 = (u & 3) * 64; drow0 = n0; }
#pragma unroll
    for (int it = 0; it < 16; ++it) {
        int idx = tid + it * 256, r = idx >> 6, c = idx & 63;
        t[r][c] = src[(size_t)(k0 + r) * srcN + n0 + c];     // coalesced read
    }
    __syncthreads();
#pragma unroll
    for (int it = 0; it < 16; ++it) {
        int idx = tid + it * 256, r = idx >> 6, c = idx & 63;
        dst[(size_t)(drow0 + r) * 256 + k0 + c] = f2bf(t[c][r]);  // coalesced write
    }
}

// ---------- GEMM core v5: tile 64x128, single-barrier double-buffered ----------
// 4 waves (2x2), wave tile 32x64 = 2x4 frags of 16x16x32. BK=32.
// Half-latency blocks + 2x grid vs 128-tile: kills tail/fill waste.
// out_mode: 0 = f32 [M,N]; 2 = fp16 [M,N]; 3 = fp16 scattered to
//           vproj_t[(b*8+h)*NV + pix][32] with h=col>>5, ch=col&31.
#define LDP 40               // padded LDS row (bf16 elems)
#define ABUF (64 * LDP)      // ushort elems per A buffer
#define BBUF (128 * LDP)     // ushort elems per B buffer

template<int AF32>
static __device__ __forceinline__ void gemm_core5(
    const void* __restrict__ Aptr, const ushort* __restrict__ Bt,
    const float* __restrict__ bias, void* __restrict__ Cout,
    int M, int N, int out_mode, int mblk, int nblk,
    ushort* sA, ushort* sB) {
    const int tid = threadIdx.x;
    const int wid = tid >> 6;
    const int lane = tid & 63;
    const int row0 = mblk * 64;
    const int col0 = nblk * 128;
    const int wr = (wid >> 1) * 32;
    const int wc = (wid & 1) * 64;

    f32x4 acc[2][4];
#pragma unroll
    for (int m = 0; m < 2; ++m)
#pragma unroll
        for (int n = 0; n < 4; ++n) acc[m][n] = (f32x4){0.f, 0.f, 0.f, 0.f};

    const int r0 = tid >> 2;          // 0..63
    const int seg = tid & 3;

    float4 rf[2];                     // f32 A staging (1 row-chunk x 2 float4)
    uint4  ra;                        // bf16 A staging
    uint4  rb[2];                     // B staging (rows r0, r0+64)

    auto REGLOAD = [&](int t) {
        int kk = t * 32;
        int gr = row0 + r0; gr = gr < M ? gr : M - 1;
        if (AF32) {
            const float* Af = (const float*)Aptr + (size_t)gr * 256 + kk + seg * 8;
            rf[0] = *reinterpret_cast<const float4*>(Af);
            rf[1] = *reinterpret_cast<const float4*>(Af + 4);
        } else {
            ra = *reinterpret_cast<const uint4*>((const ushort*)Aptr + (size_t)gr * 256 + kk + seg * 8);
        }
        rb[0] = *reinterpret_cast<const uint4*>(Bt + (size_t)(col0 + r0) * 256 + kk + seg * 8);
        rb[1] = *reinterpret_cast<const uint4*>(Bt + (size_t)(col0 + r0 + 64) * 256 + kk + seg * 8);
    };
    auto STORE = [&](int buf) {
        uint4 wa;
        if (AF32) {
            wa.x = cvtpk_bf16(rf[0].x, rf[0].y);
            wa.y = cvtpk_bf16(rf[0].z, rf[0].w);
            wa.z = cvtpk_bf16(rf[1].x, rf[1].y);
            wa.w = cvtpk_bf16(rf[1].z, rf[1].w);
        } else {
            wa = ra;
        }
        *reinterpret_cast<uint4*>(&sA[buf * ABUF + r0 * LDP + seg * 8]) = wa;
        *reinterpret_cast<uint4*>(&sB[buf * BBUF + r0 * LDP + seg * 8]) = rb[0];
        *reinterpret_cast<uint4*>(&sB[buf * BBUF + (r0 + 64) * LDP + seg * 8]) = rb[1];
    };
    auto COMPUTE = [&](int buf) {
        const int rbase = lane & 15;
        const int g8 = (lane >> 4) * 8;
        short8 a[2], b[4];
#pragma unroll
        for (int m = 0; m < 2; ++m)
            a[m] = *reinterpret_cast<const short8*>(&sA[buf * ABUF + (wr + m * 16 + rbase) * LDP + g8]);
#pragma unroll
        for (int n = 0; n < 4; ++n)
            b[n] = *reinterpret_cast<const short8*>(&sB[buf * BBUF + (wc + n * 16 + rbase) * LDP + g8]);
#pragma unroll
        for (int m = 0; m < 2; ++m)
#pragma unroll
            for (int n = 0; n < 4; ++n)
                acc[m][n] = __builtin_amdgcn_mfma_f32_16x16x32_bf16(a[m], b[n], acc[m][n], 0, 0, 0);
    };

    REGLOAD(0);
    STORE(0);
#pragma unroll
    for (int t = 0; t < 8; ++t) {
        __syncthreads();                       // buf[t&1] stores visible
        if (t < 7) REGLOAD(t + 1);             // in flight during COMPUTE
        COMPUTE(t & 1);
        if (t < 7) STORE((t + 1) & 1);         // other buffer: no extra barrier
    }

    // epilogue: lane holds C[row=(lane>>4)*4+j][col=lane&15] per fragment
    const int lr = (lane >> 4) * 4;
    const int lc = lane & 15;
#pragma unroll
    for (int m = 0; m < 2; ++m) {
#pragma unroll
        for (int n = 0; n < 4; ++n) {
            int gcol = col0 + wc + n * 16 + lc;
            float bv = bias[gcol];
#pragma unroll
            for (int j = 0; j < 4; ++j) {
                int grow = row0 + wr + m * 16 + lr + j;
                if (grow < M) {
                    float vv = acc[m][n][j] + bv;
                    if (out_mode == 0) {
                        ((float*)Cout)[(size_t)grow * N + gcol] = vv;
                    } else if (out_mode == 2) {
                        ((ushort*)Cout)[(size_t)grow * N + gcol] = (ushort)(cvtpk_f16(vv, vv) & 0xffffu);
                    } else {   // mode 3: transposed fp16 value layout [b*8+h][pix][32]
                        int bb = grow >= NV;
                        int pix = grow - bb * NV;
                        int h = gcol >> 5, ch = gcol & 31;
                        ((ushort*)Cout)[(((size_t)(bb * 8 + h)) * NV + pix) * 32 + ch] =
                            (ushort)(cvtpk_f16(vv, vv) & 0xffffu);
                    }
                }
            }
        }
    }
}

// merged GEMM1 (value->vproj_t fp16, y=0..1) + GEMM2 (query->offattn fp16, y=2..4)
__global__ __launch_bounds__(256, 4) void gemm_fused(
    const float* __restrict__ value, const float* __restrict__ query,
    const ushort* __restrict__ tWv, const ushort* __restrict__ tWoa,
    const float* __restrict__ bval, const float* __restrict__ boa,
    ushort* __restrict__ vproj_t, ushort* __restrict__ offattn) {
    __shared__ ushort sA[2 * ABUF];
    __shared__ ushort sB[2 * BBUF];
    const bool g1 = blockIdx.y < 2;
    gemm_core5<1>(g1 ? (const void*)value : (const void*)query,
                  g1 ? tWv : tWoa, g1 ? bval : boa,
                  g1 ? (void*)vproj_t : (void*)offattn,
                  BQ, g1 ? 256 : 384, g1 ? 3 : 2,
                  blockIdx.x, g1 ? blockIdx.y : blockIdx.y - 2, sA, sB);
}

__global__ __launch_bounds__(256, 4) void gemm_out(
    const ushort* __restrict__ outacc, const ushort* __restrict__ tWu,
    const float* __restrict__ bout, float* __restrict__ dout) {
    __shared__ ushort sA[2 * ABUF];
    __shared__ ushort sB[2 * BBUF];
    gemm_core5<0>(outacc, tWu, bout, dout, BQ, 256, 0, blockIdx.x, blockIdx.y, sA, sB);
}

// ---------- softmax + bilinear sampling + head-weighted accumulation ----------
// (unchanged: at its memory-system roofline, 54us invariant across structures)
__global__ __launch_bounds__(256, 4) void msda_sample(
    const ushort* __restrict__ offattn,  // fp16 [BQ, 384] : 256 offsets + 128 logits
    const float* __restrict__ refp,      // [B, NQ, 4, 2]
    const ushort* __restrict__ vt,       // fp16 [B*8][NV][32]
    ushort* __restrict__ out_acc) {      // bf16 [BQ, 256]
    __shared__ int2 s_ad[4][256];        // 8KB : (addr_row0, addr_row1)
    __shared__ uint s_w[4][256];         // 4KB : packed f16 (w_y0, w_y1)

    const int tid = threadIdx.x;
    const int qi = tid >> 6;
    const int lane = tid & 63;
    const int bq = blockIdx.x * 4 + qi;  // 26588 = 4 * 6647 exact
    const int b = bq / NQ;
    const int q = bq - b * NQ;
    const int h = lane >> 3;

    const ushort* oa = offattn + (size_t)bq * 384;
    const int t0 = lane * 2;             // t = h*16 + s
    uint lgu = *reinterpret_cast<const uint*>(oa + 256 + t0);
    float lg0 = f16lo(lgu), lg1 = f16hi(lgu);
    float m = fmaxf(lg0, lg1);
    m = fmaxf(m, __shfl_xor(m, 1));
    m = fmaxf(m, __shfl_xor(m, 2));
    m = fmaxf(m, __shfl_xor(m, 4));      // max over the head's 16 logits
    float e0 = __expf(lg0 - m), e1 = __expf(lg1 - m);
    float ssum = e0 + e1;
    ssum += __shfl_xor(ssum, 1);
    ssum += __shfl_xor(ssum, 2);
    ssum += __shfl_xor(ssum, 4);
    float inv = 1.f / ssum;

    uint2 offu = *reinterpret_cast<const uint2*>(oa + 2 * t0);  // 4 fp16
    const int l = (t0 >> 2) & 3;
    const int   Wi = (l == 0) ? 100 : (l == 1) ? 50 : (l == 2) ? 25 : 13;
    const int   st = (l == 0) ? 0 : (l == 1) ? 10000 : (l == 2) ? 12500 : 13125;
    const float Wf = (float)Wi;
    float rx = refp[(((size_t)b * NQ + q) * 4 + l) * 2 + 0];
    float ry = refp[(((size_t)b * NQ + q) * 4 + l) * 2 + 1];
    const int vbase = (b * 8 + h) * NV * 64;      // byte base of this head's plane

#pragma unroll
    for (int j = 0; j < 2; ++j) {
        float e = (j ? e1 : e0) * inv;
        float ox = j ? f16lo(offu.y) : f16lo(offu.x);
        float oy = j ? f16hi(offu.y) : f16hi(offu.x);
        float x = fmaf(rx, Wf, ox) - 0.5f;
        float y = fmaf(ry, Wf, oy) - 0.5f;
        float x0f = floorf(x), y0f = floorf(y);
        float fx = x - x0f, fy = y - y0f;
        int x0 = (int)x0f, y0 = (int)y0f;
        float wx0 = (x0 >= 0 && x0 < Wi)         ? e * (1.f - fx) : 0.f;
        float wx1 = (x0 + 1 >= 0 && x0 + 1 < Wi) ? e * fx         : 0.f;
        float wy0 = (y0 >= 0 && y0 < Wi)         ? (1.f - fy) : 0.f;
        float wy1 = (y0 + 1 >= 0 && y0 + 1 < Wi) ? fy         : 0.f;
        int px0 = min(max(x0, 0), Wi - 1) * 64;
        int px1 = min(max(x0 + 1, 0), Wi - 1) * 64;
        int a0 = vbase + (st + min(max(y0, 0), Wi - 1) * Wi) * 64;
        int a1 = vbase + (st + min(max(y0 + 1, 0), Wi - 1) * Wi) * 64;
        int s = 2 * (lane & 7) + j;
        int u = ((s ^ h) << 4) + (h << 1);
        s_ad[qi][u]     = make_int2(a0 + px0, a1 + px0);
        s_ad[qi][u + 1] = make_int2(a0 + px1, a1 + px1);
        s_w[qi][u]      = cvtpk_f16(wx0 * wy0, wx0 * wy1);
        s_w[qi][u + 1]  = cvtpk_f16(wx1 * wy0, wx1 * wy1);
    }
    __syncthreads();

    const int xbit = (lane >> 2) & 1;
    const int cg16 = (lane & 3) * 16;
    const char* vtc = (const char*)vt;

    int2 A[16]; uint Wp[16];
#pragma unroll
    for (int ss = 0; ss < 16; ++ss) {
        int u = ((ss ^ h) << 4) + (h << 1) + xbit;
        int2 a = s_ad[qi][u];
        A[ss] = make_int2(a.x + cg16, a.y + cg16);
        Wp[ss] = s_w[qi][u];
    }

    float acc[8] = {0.f, 0.f, 0.f, 0.f, 0.f, 0.f, 0.f, 0.f};
#pragma unroll
    for (int ss = 0; ss < 16; ++ss) {
        uint4 g0 = *reinterpret_cast<const uint4*>(vtc + (uint)A[ss].x);
        uint4 g1 = *reinterpret_cast<const uint4*>(vtc + (uint)A[ss].y);
        uint w = Wp[ss];
        acc[0] = fmamix_ll(acc[0], g0.x, w); acc[1] = fmamix_hl(acc[1], g0.x, w);
        acc[2] = fmamix_ll(acc[2], g0.y, w); acc[3] = fmamix_hl(acc[3], g0.y, w);
        acc[4] = fmamix_ll(acc[4], g0.z, w); acc[5] = fmamix_hl(acc[5], g0.z, w);
        acc[6] = fmamix_ll(acc[6], g0.w, w); acc[7] = fmamix_hl(acc[7], g0.w, w);
        acc[0] = fmamix_lh(acc[0], g1.x, w); acc[1] = fmamix_hh(acc[1], g1.x, w);
        acc[2] = fmamix_lh(acc[2], g1.y, w); acc[3] = fmamix_hh(acc[3], g1.y, w);
        acc[4] = fmamix_lh(acc[4], g1.z, w); acc[5] = fmamix_hh(acc[5], g1.z, w);
        acc[6] = fmamix_lh(acc[6], g1.w, w); acc[7] = fmamix_hh(acc[7], g1.w, w);
    }

#pragma unroll
    for (int i = 0; i < 8; ++i) acc[i] += __shfl_xor(acc[i], 4);   // sum x-corners
    if (xbit == 0) {
        uint4 o;
        o.x = cvtpk_bf16(acc[0], acc[1]);
        o.y = cvtpk_bf16(acc[2], acc[3]);
        o.z = cvtpk_bf16(acc[4], acc[5]);
        o.w = cvtpk_bf16(acc[6], acc[7]);
        *reinterpret_cast<uint4*>(out_acc + (size_t)bq * 256 + h * 32 + (lane & 3) * 8) = o;
    }
}

// ---------- launch ----------
extern "C" void kernel_launch(void* const* d_in, const int* in_sizes, int n_in,
                              void* d_out, int out_size, void* d_ws, size_t ws_size,
                              hipStream_t stream) {
    const float* query  = (const float*)d_in[0];
    const float* value  = (const float*)d_in[1];
    const float* refp   = (const float*)d_in[2];
    const float* W_off  = (const float*)d_in[5];
    const float* b_off  = (const float*)d_in[6];
    const float* W_attn = (const float*)d_in[7];
    const float* b_attn = (const float*)d_in[8];
    const float* W_val  = (const float*)d_in[9];
    const float* b_val  = (const float*)d_in[10];
    const float* W_out  = (const float*)d_in[11];
    const float* b_out  = (const float*)d_in[12];

    const size_t ROWB = (size_t)BQ * 256 * 2;   // bytes of one 16-bit [BQ,256] buffer
    char* ws = (char*)d_ws;
    ushort* vproj_t = (ushort*)(ws);                               // [B*8][NV][32] fp16
    ushort* outacc  = (ushort*)(ws + ROWB);                        // [BQ,256] bf16
    ushort* offattn = (ushort*)(ws + 2 * ROWB);                    // [BQ,384] fp16
    char*   wbase   = ws + 2 * ROWB + (size_t)BQ * 384 * 2;
    ushort* tWv  = (ushort*)(wbase);
    ushort* tWoa = tWv + 65536;
    ushort* tWu  = tWoa + 98304;
    float*  boa  = (float*)(tWu + 65536);

    prep_weights<<<57, 256, 0, stream>>>(
        W_val, W_off, W_attn, W_out, b_off, b_attn, tWv, tWoa, tWu, boa);

    gemm_fused<<<dim3(416, 5), 256, 0, stream>>>(
        value, query, tWv, tWoa, b_val, boa, vproj_t, offattn);

    msda_sample<<<BQ / 4, 256, 0, stream>>>(offattn, refp, vproj_t, outacc);

    gemm_out<<<dim3(416, 2), 256, 0, stream>>>(outacc, tWu, b_out, (float*)d_out);
}